// Round 6
// baseline (556.145 us; speedup 1.0000x reference)
//
#include <hip/hip_runtime.h>
#include <hip/hip_bf16.h>

#define BB 512
#define SS 1024
#define NI 20
#define HH 64
#define NG 256   // 4*H
#define MB4 4    // batches per block (x2 dirs in-lane)
#define PAD 80   // h-row stride in f16
#define TROW 260 // x-table row stride (floats); [tok][unit][4tt], 16B rows

typedef unsigned short u16;
typedef unsigned int u32;
typedef unsigned long long u64;
typedef _Float16 f16;
typedef f16 f16x8 __attribute__((ext_vector_type(8)));
typedef float f32x4 __attribute__((ext_vector_type(4)));

#define LOG2E 1.4426950408889634f

__device__ __forceinline__ float bf2f(u16 b) { return __uint_as_float(((u32)b) << 16); }
// mode==1: data is bf16; mode==0: data is fp32
__device__ __forceinline__ float ldw(const void* p, int idx, int mode) {
  return mode ? bf2f(((const u16*)p)[idx]) : ((const float*)p)[idx];
}
__device__ __forceinline__ float frcp(float x) { return __builtin_amdgcn_rcpf(x); }
__device__ __forceinline__ float fexp2(float x) { return __builtin_amdgcn_exp2f(x); }

// ---- BiLSTM, dual-chain-per-lane edition. Ledger r0-r5: the r0 4-wave MB4
// step body is locally optimal; extra WAVES on the barrier lose (r1/r3); wave-
// private dup loses (r4); conv fusion contends (r5). This round: interleave
// TWO independent chains (fwd+bwd of the SAME 4 batches) in each wave's
// instruction stream. Chain A's exposed latency (h LDS round trip, MFMA tail,
// exp2 chain -- ~440 of 711 cyc/step) is filled by chain B's instructions in
// program order; per-chain issue work unchanged; ONE barrier per step-pair.
// Block = 4 batches x both dirs, 128 blocks x 256 thr. Lane (l,q) = cells
// (batch q, unit 16w+l) x {fwd,bwd}; A-rows dup h[l>>2] 4x per dir.
// wx via one ds_read_b128/chain (r5-verified [tok][unit][4tt] table).
// T-cap = maxlen4+96 (r2-verified fixpoint). Weights prescaled: i,f,o rows by
// -log2e, g rows by +2log2e (exp2-ready).
__global__ __launch_bounds__(256)
void lstm_kernel(const void* in1,
                 const void* Wih_f, const void* Whh_f, const void* b_f,
                 const void* Wih_b, const void* Whh_b, const void* b_b,
                 short* toks_g, int* lens, float* hout) {
  int bx = blockIdx.x;          // 0..127
  int b0 = bx * MB4;
  int t = threadIdx.x;
  int w = t >> 6, lane = t & 63, l = lane & 15, q = lane >> 4;
  int bsel = l >> 2;            // batch whose h this lane's A-row carries

  __shared__ __align__(16) float table[2][21 * TROW]; // 43.7 KB; doubles as extract staging
  __shared__ __align__(16) f16 hbuf[2][2][MB4][PAD];  // [dir][phase][batch][unit]
  __shared__ short tok_s[SS * MB4];                   // [pos][m], stores tok+1
  __shared__ u64 red[256];
  __shared__ int mode_sh;

  // ---- mode probe: b_f read as bf16; fp32 shows wild exponents ----
  if (t == 0) mode_sh = 1;
  __syncthreads();
  {
    float v = bf2f(((const u16*)b_f)[t]);
    if (!(fabsf(v) < 1000.0f)) atomicAnd(&mode_sh, 0);
  }
  __syncthreads();
  int mode = mode_sh;

  // ---- token extraction for this block's 4 batches (staged through table) ----
  u64 cnt = 0;  // packed 4x16-bit valid counts
  for (int m = 0; m < MB4; ++m) {
    if (mode) {
      u32* st = (u32*)&table[0][0];
      for (int k0 = 0; k0 < 4; ++k0) {
        const u32* src = (const u32*)in1 + ((size_t)(b0 + m) * SS + k0 * 256) * 10;
#pragma unroll
        for (int i = 0; i < 10; ++i) st[t + i * 256] = src[t + i * 256];  // coalesced
        __syncthreads();
        const u32* row = st + t * 10;
        int tok = -1;
#pragma unroll
        for (int ww = 0; ww < 10; ++ww) {
          u32 u = row[ww];
          if (u & 0xFFFFu) tok = 2 * ww;
          if (u >> 16)     tok = 2 * ww + 1;
        }
        tok_s[(k0 * 256 + t) * MB4 + m] = (short)(tok + 1);
        toks_g[(size_t)(b0 + m) * SS + k0 * 256 + t] = (short)tok;
        cnt += (u64)(tok >= 0) << (16 * m);
        __syncthreads();
      }
    } else {
      float4* st = (float4*)&table[0][0];
      for (int k0 = 0; k0 < 4; ++k0) {
        const float4* src = (const float4*)((const float*)in1 + ((size_t)(b0 + m) * SS + k0 * 256) * 20);
#pragma unroll
        for (int i = 0; i < 5; ++i) st[t + i * 256] = src[t + i * 256];  // coalesced 16B/lane
        __syncthreads();
        const float* row = (const float*)&table[0][0] + t * 20;
        int tok = -1;
#pragma unroll
        for (int ww = 0; ww < 20; ++ww)
          if (row[ww] != 0.f) tok = ww;
        tok_s[(k0 * 256 + t) * MB4 + m] = (short)(tok + 1);
        toks_g[(size_t)(b0 + m) * SS + k0 * 256 + t] = (short)tok;
        cnt += (u64)(tok >= 0) << (16 * m);
        __syncthreads();
      }
    }
  }
  // lens: packed u64 tree reduction
  red[t] = cnt;
  __syncthreads();
  for (int stp = 128; stp > 0; stp >>= 1) {
    if (t < stp) red[t] += red[t + stp];
    __syncthreads();
  }
  if (t < MB4)
    lens[b0 + t] = (int)((red[0] >> (16 * t)) & 0xFFFFull);

  // ---- step-count cap: >=96 all-pad steps == fixpoint == reference ----
  int T;
  {
    u64 pk = red[0];
    int maxlen = 0;
#pragma unroll
    for (int m = 0; m < MB4; ++m) {
      int L = (int)((pk >> (16 * m)) & 0xFFFFull);
      maxlen = L > maxlen ? L : maxlen;
    }
    T = maxlen + 96;
    if (T > SS) T = SS;
  }
  __syncthreads();

  // ---- x-projection tables, both dirs: table[d][tok+1][u][tt] = scl_tt*(W_ih[64tt+u][tok]+b) ----
  for (int idx = t; idx < 2 * 21 * 256; idx += 256) {
    int d = idx >= 21 * 256;
    int loc = idx - d * 21 * 256;
    int r = loc >> 8, g = loc & 255;
    const void* Wd = d ? Wih_b : Wih_f;
    const void* bd = d ? b_b : b_f;
    float scl = ((g >> 6) == 2) ? (2.f * LOG2E) : (-LOG2E);
    float v = ldw(bd, g, mode);
    if (r > 0) v += ldw(Wd, g * NI + (r - 1), mode);
    table[d][r * TROW + (g & 63) * 4 + (g >> 6)] = scl * v;
  }
  // ---- W_hh B-fragments, both dirs: n=lane&15 -> gate col (unit 16w+l, tt), k=q*8+j ----
  f16x8 Bf[2][4][2];
#pragma unroll
  for (int d = 0; d < 2; ++d) {
    const void* Whh = d ? Whh_b : Whh_f;
#pragma unroll
    for (int tt = 0; tt < 4; ++tt) {
      float scl = (tt == 2) ? (2.f * LOG2E) : (-LOG2E);
      int g = 64 * tt + 16 * w + l;
#pragma unroll
      for (int kc = 0; kc < 2; ++kc) {
        f16x8 v;
#pragma unroll
        for (int j = 0; j < 8; ++j)
          v[j] = (f16)(scl * ldw(Whh, g * HH + kc * 32 + q * 8 + j, mode));
        Bf[d][tt][kc] = v;
      }
    }
  }
  for (int idx = t; idx < 2 * 2 * MB4 * PAD; idx += 256)
    ((f16*)hbuf)[idx] = (f16)0.f;
  __syncthreads();

  float cs0 = 0.f, cs1 = 0.f, hl0 = 0.f, hl1 = 0.f;
  int jj = 16 * w + l;
  const float* tF = table[0];
  const float* tB = table[1];

  // x-pipeline prologue: wx for s=0 (regs), tok for s=1 (reg), both chains
  f32x4 wxc0 = *(const f32x4*)&tF[(int)tok_s[0 * MB4 + q] * TROW + jj * 4];
  f32x4 wxc1 = *(const f32x4*)&tB[(int)tok_s[(T - 1) * MB4 + q] * TROW + jj * 4];
  int tok10 = (int)tok_s[1 * MB4 + q];
  int tok11 = (int)tok_s[(T - 2) * MB4 + q];

#pragma unroll 1
  for (int s = 0; s < T; ++s) {
    int p = s & 1;
    // critical path: h fragments for BOTH chains (A[m=l][k=q*8+j], 4x dup rows)
    f16x8 a00 = *(const f16x8*)&hbuf[0][p][bsel][q * 8];
    f16x8 a01 = *(const f16x8*)&hbuf[0][p][bsel][32 + q * 8];
    f16x8 a10 = *(const f16x8*)&hbuf[1][p][bsel][q * 8];
    f16x8 a11 = *(const f16x8*)&hbuf[1][p][bsel][32 + q * 8];
    // off-path: wx prefetch for s+1 (b128 each), tok fetch for s+2
    f32x4 wxn0 = *(const f32x4*)&tF[tok10 * TROW + jj * 4];
    f32x4 wxn1 = *(const f32x4*)&tB[tok11 * TROW + jj * 4];
    tok10 = (int)tok_s[((s + 2) & (SS - 1)) * MB4 + q];          // wrapped values unused
    tok11 = (int)tok_s[((T - 3 - s) & (SS - 1)) * MB4 + q];

    // r9-verified serial C-chain x2 chains: C-init = x-projection, 2-deep per gate
    f32x4 acc0[4], acc1[4];
#pragma unroll
    for (int tt = 0; tt < 4; ++tt) {
      f32x4 ci = {wxc0[tt], wxc0[tt], wxc0[tt], wxc0[tt]};
      acc0[tt] = __builtin_amdgcn_mfma_f32_16x16x32_f16(a00, Bf[0][tt][0], ci, 0, 0, 0);
    }
#pragma unroll
    for (int tt = 0; tt < 4; ++tt) {
      f32x4 ci = {wxc1[tt], wxc1[tt], wxc1[tt], wxc1[tt]};
      acc1[tt] = __builtin_amdgcn_mfma_f32_16x16x32_f16(a10, Bf[1][tt][0], ci, 0, 0, 0);
    }
#pragma unroll
    for (int tt = 0; tt < 4; ++tt)
      acc0[tt] = __builtin_amdgcn_mfma_f32_16x16x32_f16(a01, Bf[0][tt][1], acc0[tt], 0, 0, 0);
#pragma unroll
    for (int tt = 0; tt < 4; ++tt)
      acc1[tt] = __builtin_amdgcn_mfma_f32_16x16x32_f16(a11, Bf[1][tt][1], acc1[tt], 0, 0, 0);

    // activations (r0-verbatim math), two independent chains -- compiler
    // interleaves the exp2/rcp serial sections
    {
      float Ei = fexp2(acc0[0][0]);
      float Ef = fexp2(acc0[1][0]);
      float G  = fexp2(acc0[2][0]);
      float Eo = fexp2(acc0[3][0]);
      float Ei1 = Ei + 1.f, Ef1 = Ef + 1.f, G1 = G + 1.f, Gm = G - 1.f;
      float t1 = Ei1 * G1;
      float num = fmaf(cs0, t1, Gm * Ef1);
      float cv = num * frcp(t1 * Ef1);
      cs0 = cv;
      float C = fexp2((2.f * LOG2E) * cv);
      float hv = (C - 1.f) * frcp((Eo + 1.f) * (C + 1.f));
      hl0 = hv;
      hbuf[0][p ^ 1][q][jj] = (f16)hv;
    }
    {
      float Ei = fexp2(acc1[0][0]);
      float Ef = fexp2(acc1[1][0]);
      float G  = fexp2(acc1[2][0]);
      float Eo = fexp2(acc1[3][0]);
      float Ei1 = Ei + 1.f, Ef1 = Ef + 1.f, G1 = G + 1.f, Gm = G - 1.f;
      float t1 = Ei1 * G1;
      float num = fmaf(cs1, t1, Gm * Ef1);
      float cv = num * frcp(t1 * Ef1);
      cs1 = cv;
      float C = fexp2((2.f * LOG2E) * cv);
      float hv = (C - 1.f) * frcp((Eo + 1.f) * (C + 1.f));
      hl1 = hv;
      hbuf[1][p ^ 1][q][jj] = (f16)hv;
    }
    __syncthreads();
    wxc0 = wxn0; wxc1 = wxn1;
  }
  hout[(b0 + q) * 128 + jj] = hl0;
  hout[(b0 + q) * 128 + 64 + jj] = hl1;
}

// ---- head (r0 verbatim), latency-optimized: 512 blocks x 256 thr ----
__global__ __launch_bounds__(256)
void head_kernel(const void* conv1_w, const void* conv2_w, const void* conv2_b,
                 const void* fc1_w, const void* fc1_b,
                 const void* fc2_w, const void* fc2_b,
                 const void* bvec, const short* toks, const int* lens,
                 const float* hout, void* out) {
  int b = blockIdx.x;
  int t = threadIdx.x;  // 256 threads
  __shared__ float c1w[400];
  __shared__ short tok_s[SS];
  __shared__ float pav[3][80];
  __shared__ float avg[80];
  __shared__ float cpart[2][100];
  __shared__ float merged[228];
  __shared__ float fpart[4][64];
  __shared__ float fc1v[64];
  __shared__ float f2p[2][64];
  __shared__ int mode_sh;

  if (t == 0) mode_sh = 1;
  __syncthreads();
  {
    float v = bf2f(((const u16*)bvec)[t]);
    if (!(fabsf(v) < 1000.0f)) atomicAnd(&mode_sh, 0);
  }
  __syncthreads();
  int mode = mode_sh;

  for (int i = t; i < 400; i += 256) c1w[i] = ldw(conv1_w, i, mode);
  for (int s = t; s < SS; s += 256) tok_s[s] = toks[(size_t)b * SS + s];
  __syncthreads();

  int len = lens[b];
  int bw = len >> 2;
  // ragged 4-bin mean: 240 threads = 80 (k,cc) units x 3 segments; 4 independent
  // partial-sum chains per thread so the tok->c1w dependent LDS reads pipeline.
  if (t < 240) {
    int seg = t / 80;
    int u = t - seg * 80;
    int k = u / 20, cc = u % 20;
    int base = k * bw;
    int s0 = base + (seg * bw) / 3;
    int s1 = base + ((seg + 1) * bw) / 3;
    float p0 = 0.f, p1 = 0.f, p2 = 0.f, p3 = 0.f;
    int s = s0;
    for (; s + 4 <= s1; s += 4) {
      // faithful torch reshape: flat f = s*20+cc of the [20,1024] map
      int f0 = s * 20 + cc, f1 = f0 + 20, f2 = f0 + 40, f3 = f0 + 60;
      int tk0 = tok_s[f0 & 1023];
      int tk1 = tok_s[f1 & 1023];
      int tk2 = tok_s[f2 & 1023];
      int tk3 = tok_s[f3 & 1023];
      if (tk0 >= 0) p0 += c1w[(f0 >> 10) * 20 + tk0];
      if (tk1 >= 0) p1 += c1w[(f1 >> 10) * 20 + tk1];
      if (tk2 >= 0) p2 += c1w[(f2 >> 10) * 20 + tk2];
      if (tk3 >= 0) p3 += c1w[(f3 >> 10) * 20 + tk3];
    }
    for (; s < s1; ++s) {
      int f = s * 20 + cc;
      int tk = tok_s[f & 1023];
      if (tk >= 0) p0 += c1w[(f >> 10) * 20 + tk];
    }
    pav[seg][u] = (p0 + p1) + (p2 + p3);
  }
  __syncthreads();
  if (t < 80) avg[t] = (pav[0][t] + pav[1][t] + pav[2][t]) / (float)bw;
  __syncthreads();

  // conv2: 200 threads = 100 outputs x 2 K-halves of 40, unroll 8
  if (t < 200) {
    int half = t / 100, o = t - half * 100;
    float dot = 0.f;
    int q0 = half * 40;
#pragma unroll 8
    for (int q = q0; q < q0 + 40; ++q)
      dot = fmaf(avg[q], ldw(conv2_w, o * 80 + q, mode), dot);
    cpart[half][o] = dot;
  }
  if (t < 128) merged[t] = hout[b * 128 + t];  // [h_fw | h_bw]
  __syncthreads();
  if (t < 100) {
    float dot = cpart[0][t] + cpart[1][t] + ldw(conv2_b, t, mode);
    merged[128 + t] = dot > 0.f ? dot : 0.f;  // relu
  }
  __syncthreads();

  // fc1: 256 threads = 64 outputs x 4 K-chunks of 57, unroll 8
  {
    int o = t & 63, ch = t >> 6;
    float v = 0.f;
    int m0 = ch * 57;
#pragma unroll 8
    for (int m = m0; m < m0 + 57; ++m)
      v = fmaf(merged[m], ldw(fc1_w, o * 228 + m, mode), v);
    fpart[ch][o] = v;
  }
  __syncthreads();
  if (t < 64)
    fc1v[t] = fpart[0][t] + fpart[1][t] + fpart[2][t] + fpart[3][t] + ldw(fc1_b, t, mode);
  __syncthreads();

  // fc2: 128 threads compute products, tree-reduce
  if (t < 128) {
    int o = t >> 6, m = t & 63;
    f2p[o][m] = fc1v[m] * ldw(fc2_w, o * 64 + m, mode);
  }
  __syncthreads();
  for (int stp = 32; stp > 0; stp >>= 1) {
    if (t < 128) {
      int o = t >> 6, m = t & 63;
      if (m < stp) f2p[o][m] += f2p[o][m + stp];
    }
    __syncthreads();
  }
  if (t == 0) {
    float x0 = f2p[0][0] + ldw(fc2_b, 0, mode);
    float x1 = f2p[1][0] + ldw(fc2_b, 1, mode);
    float mx = fmaxf(x0, x1);
    float e0 = fexp2(LOG2E * (x0 - mx)), e1 = fexp2(LOG2E * (x1 - mx));
    float inv = frcp(e0 + e1);
    if (mode) {
      ((__hip_bfloat16*)out)[b * 2 + 0] = __float2bfloat16(e0 * inv);
      ((__hip_bfloat16*)out)[b * 2 + 1] = __float2bfloat16(e1 * inv);
    } else {
      ((float*)out)[b * 2 + 0] = e0 * inv;
      ((float*)out)[b * 2 + 1] = e1 * inv;
    }
  }
}

extern "C" void kernel_launch(void* const* d_in, const int* in_sizes, int n_in,
                              void* d_out, int out_size, void* d_ws, size_t ws_size,
                              hipStream_t stream) {
  (void)in_sizes; (void)n_in; (void)out_size; (void)ws_size;
  char* ws = (char*)d_ws;
  int*   lens = (int*)(ws + 256);                             // 2 KB
  short* toks = (short*)(ws + 256 + 2048);                    // 1 MB
  float* hout = (float*)(ws + 256 + 2048 + (size_t)BB * SS * sizeof(short)); // 256 KB

  lstm_kernel<<<128, 256, 0, stream>>>(d_in[0],
                                       d_in[1], d_in[2], d_in[3],
                                       d_in[4], d_in[5], d_in[6],
                                       toks, lens, hout);
  head_kernel<<<BB, 256, 0, stream>>>(d_in[7], d_in[8], d_in[9],
                                      d_in[10], d_in[11], d_in[12], d_in[13],
                                      d_in[3], toks, lens, hout, d_out);
}

// Round 7
// 415.779 us; speedup vs baseline: 1.3376x; 1.3376x over previous
//
#include <hip/hip_runtime.h>
#include <hip/hip_bf16.h>

#define BB 512
#define SS 1024
#define NI 20
#define HH 64
#define NG 256   // 4*H
#define MB4 4    // batch-dirs per block (1 cell per lane)
#define PAD 80   // h-row stride in f16
#define TROW 260 // x-table row stride (floats); [tok][unit][4tt], 16B rows

typedef unsigned short u16;
typedef unsigned int u32;
typedef unsigned long long u64;
typedef _Float16 f16;
typedef f16 f16x8 __attribute__((ext_vector_type(8)));
typedef float f32x4 __attribute__((ext_vector_type(4)));

#define LOG2E 1.4426950408889634f

__device__ __forceinline__ float bf2f(u16 b) { return __uint_as_float(((u32)b) << 16); }
// mode==1: data is bf16; mode==0: data is fp32
__device__ __forceinline__ float ldw(const void* p, int idx, int mode) {
  return mode ? bf2f(((const u16*)p)[idx]) : ((const float*)p)[idx];
}
__device__ __forceinline__ float frcp(float x) { return __builtin_amdgcn_rcpf(x); }
__device__ __forceinline__ float fexp2(float x) { return __builtin_amdgcn_exp2f(x); }

// ---- BiLSTM: r0-verbatim structure (the r0-r6 ledger: every structural
// alternative -- MB1, 8-wave barrier, 1-chain/wave dup, conv fusion,
// dual-dir-in-lane -- lost; 4-batch shared-A / 8-MFMA / 4-wave-barrier is the
// local optimum). Only the two measured-positive micro-deltas are applied:
// (1) r5's x-table layout [tok][unit][4tt] -> per-step wx prefetch is ONE
//     ds_read_b128 instead of 4 scalar LDS reads (bank conflicts -44%).
// (2) r2's step-count cap T = min(1024, maxlen4+96): >=96 all-pad steps pin
//     (h,c) at the weights' fixpoint (contraction ~0.55/step) == reference
//     within 1e-18; wall-neutral, trims average block time.
// 256 blocks x 256 thr, 1 block/CU. Block = (dir, 4 batches). Wave w owns
// units 16w..16w+15, 4 gate types in-lane; lane (l,q) = cell (batch q,
// unit 16w+l); A-rows dup h[l>>2] 4x. x-projection rides MFMA C-init.
// Weights prescaled: i,f,o rows by -log2e, g rows by +2log2e (exp2-ready).
__global__ __launch_bounds__(256)
void lstm_kernel(const void* in1,
                 const void* Wih_f, const void* Whh_f, const void* b_f,
                 const void* Wih_b, const void* Whh_b, const void* b_b,
                 short* toks_g, int* lens, float* hout) {
  int bx = blockIdx.x;          // 0..255
  int dir = bx >> 7;
  int b0 = (bx & 127) * MB4;
  int t = threadIdx.x;
  int w = t >> 6, lane = t & 63, l = lane & 15, q = lane >> 4;
  int bsel = l >> 2;            // batch whose h this lane's A-row carries

  __shared__ __align__(16) float table[21 * TROW];  // 21.8 KB; doubles as extract staging
  __shared__ __align__(16) f16 hbuf[2][MB4][PAD];
  __shared__ short tok_s[SS * MB4];                 // [pos][m], stores tok+1
  __shared__ u64 red[256];
  __shared__ int mode_sh;

  // ---- mode probe: b_f read as bf16; fp32 shows wild exponents ----
  if (t == 0) mode_sh = 1;
  __syncthreads();
  {
    float v = bf2f(((const u16*)b_f)[t]);
    if (!(fabsf(v) < 1000.0f)) atomicAnd(&mode_sh, 0);
  }
  __syncthreads();
  int mode = mode_sh;
  const void* Wih = dir ? Wih_b : Wih_f;
  const void* Whh = dir ? Whh_b : Whh_f;
  const void* bv  = dir ? b_b   : b_f;

  // ---- token extraction for this block's 4 batches (staged through `table` memory) ----
  u64 cnt = 0;  // packed 4x16-bit valid counts
  for (int m = 0; m < MB4; ++m) {
    if (mode) {
      u32* st = (u32*)table;
      for (int k0 = 0; k0 < 4; ++k0) {
        const u32* src = (const u32*)in1 + ((size_t)(b0 + m) * SS + k0 * 256) * 10;
#pragma unroll
        for (int i = 0; i < 10; ++i) st[t + i * 256] = src[t + i * 256];  // coalesced
        __syncthreads();
        const u32* row = st + t * 10;
        int tok = -1;
#pragma unroll
        for (int ww = 0; ww < 10; ++ww) {
          u32 u = row[ww];
          if (u & 0xFFFFu) tok = 2 * ww;
          if (u >> 16)     tok = 2 * ww + 1;
        }
        tok_s[(k0 * 256 + t) * MB4 + m] = (short)(tok + 1);
        if (dir == 0) toks_g[(size_t)(b0 + m) * SS + k0 * 256 + t] = (short)tok;
        cnt += (u64)(tok >= 0) << (16 * m);
        __syncthreads();
      }
    } else {
      float4* st = (float4*)table;
      for (int k0 = 0; k0 < 4; ++k0) {
        const float4* src = (const float4*)((const float*)in1 + ((size_t)(b0 + m) * SS + k0 * 256) * 20);
#pragma unroll
        for (int i = 0; i < 5; ++i) st[t + i * 256] = src[t + i * 256];  // coalesced 16B/lane
        __syncthreads();
        const float* row = (const float*)table + t * 20;
        int tok = -1;
#pragma unroll
        for (int ww = 0; ww < 20; ++ww)
          if (row[ww] != 0.f) tok = ww;
        tok_s[(k0 * 256 + t) * MB4 + m] = (short)(tok + 1);
        if (dir == 0) toks_g[(size_t)(b0 + m) * SS + k0 * 256 + t] = (short)tok;
        cnt += (u64)(tok >= 0) << (16 * m);
        __syncthreads();
      }
    }
  }
  // lens: packed u64 tree reduction (fwd blocks export)
  red[t] = cnt;
  __syncthreads();
  for (int stp = 128; stp > 0; stp >>= 1) {
    if (t < stp) red[t] += red[t + stp];
    __syncthreads();
  }
  if (dir == 0 && t < MB4)
    lens[b0 + t] = (int)((red[0] >> (16 * t)) & 0xFFFFull);

  // ---- step-count cap: >=96 all-pad steps == fixpoint == reference ----
  int T;
  {
    u64 pk = red[0];
    int maxlen = 0;
#pragma unroll
    for (int m = 0; m < MB4; ++m) {
      int L = (int)((pk >> (16 * m)) & 0xFFFFull);
      maxlen = L > maxlen ? L : maxlen;
    }
    T = maxlen + 96;
    if (T > SS) T = SS;
  }
  __syncthreads();

  // ---- x-projection table: table[tok+1][u][tt] = scl_tt*(W_ih[64tt+u][tok]+b); row 0 = bias ----
  for (int idx = t; idx < 21 * 256; idx += 256) {
    int r = idx >> 8, g = idx & 255;
    float scl = ((g >> 6) == 2) ? (2.f * LOG2E) : (-LOG2E);
    float v = ldw(bv, g, mode);
    if (r > 0) v += ldw(Wih, g * NI + (r - 1), mode);
    table[r * TROW + (g & 63) * 4 + (g >> 6)] = scl * v;
  }
  // ---- W_hh B-fragments: n=lane&15 -> gate col (unit 16w+l, type tt), k=q*8+j ----
  f16x8 Bf[4][2];
#pragma unroll
  for (int tt = 0; tt < 4; ++tt) {
    float scl = (tt == 2) ? (2.f * LOG2E) : (-LOG2E);
    int g = 64 * tt + 16 * w + l;
#pragma unroll
    for (int kc = 0; kc < 2; ++kc) {
      f16x8 v;
#pragma unroll
      for (int j = 0; j < 8; ++j)
        v[j] = (f16)(scl * ldw(Whh, g * HH + kc * 32 + q * 8 + j, mode));
      Bf[tt][kc] = v;
    }
  }
  for (int idx = t; idx < 2 * MB4 * PAD; idx += 256)
    ((f16*)hbuf)[idx] = (f16)0.f;
  __syncthreads();

  float c_st = 0.f, hlast = 0.f;
  int jj = 16 * w + l;

  // x-pipeline prologue: wx for s=0 (regs), tok for s=1 (reg)
  f32x4 wxc;
  {
    int pos0 = dir ? (T - 1) : 0;
    wxc = *(const f32x4*)&table[(int)tok_s[pos0 * MB4 + q] * TROW + jj * 4];
  }
  int tok1;
  {
    int pos1 = dir ? (T - 2) : 1;
    tok1 = (int)tok_s[pos1 * MB4 + q];
  }

#pragma unroll 2
  for (int s = 0; s < T; ++s) {
    int p = s & 1;
    // critical path: h fragments (A[m=l][k=q*8+j] = h[bsel][k], 4x dup rows)
    f16x8 a0 = *(const f16x8*)&hbuf[p][bsel][q * 8];
    f16x8 a1 = *(const f16x8*)&hbuf[p][bsel][32 + q * 8];
    // off-path: wx prefetch for s+1 (single b128), tok fetch for s+2
    f32x4 wxn = *(const f32x4*)&table[tok1 * TROW + jj * 4];
    {
      int pos2 = (dir ? (T - 3 - s) : (s + 2)) & (SS - 1);  // wrapped values unused
      tok1 = (int)tok_s[pos2 * MB4 + q];
    }

    // r9-verified serial C-chain: C-init = x-projection, 2-deep MFMA per gate type
    f32x4 acc[4];
#pragma unroll
    for (int tt = 0; tt < 4; ++tt) {
      f32x4 ci = {wxc[tt], wxc[tt], wxc[tt], wxc[tt]};
      acc[tt] = __builtin_amdgcn_mfma_f32_16x16x32_f16(a0, Bf[tt][0], ci, 0, 0, 0);
    }
#pragma unroll
    for (int tt = 0; tt < 4; ++tt)
      acc[tt] = __builtin_amdgcn_mfma_f32_16x16x32_f16(a1, Bf[tt][1], acc[tt], 0, 0, 0);

    // activation (verified r6-r13): Ei=e^-i, Ef=e^-f, Eo=e^-o, G=e^2g
    {
      float Ei = fexp2(acc[0][0]);
      float Ef = fexp2(acc[1][0]);
      float G  = fexp2(acc[2][0]);
      float Eo = fexp2(acc[3][0]);
      float Ei1 = Ei + 1.f, Ef1 = Ef + 1.f, G1 = G + 1.f, Gm = G - 1.f;
      float t1 = Ei1 * G1;
      float num = fmaf(c_st, t1, Gm * Ef1);
      float cv = num * frcp(t1 * Ef1);
      c_st = cv;
      float C = fexp2((2.f * LOG2E) * cv);
      float hv = (C - 1.f) * frcp((Eo + 1.f) * (C + 1.f));
      hlast = hv;
      hbuf[p ^ 1][q][jj] = (f16)hv;
    }
    __syncthreads();
    wxc = wxn;
  }
  hout[(b0 + q) * 128 + dir * 64 + jj] = hlast;
}

// ---- head (r0 verbatim), latency-optimized: 512 blocks x 256 thr (8 waves/CU),
// every phase split across max threads with manual unrolling for independent
// load chains. ----
__global__ __launch_bounds__(256)
void head_kernel(const void* conv1_w, const void* conv2_w, const void* conv2_b,
                 const void* fc1_w, const void* fc1_b,
                 const void* fc2_w, const void* fc2_b,
                 const void* bvec, const short* toks, const int* lens,
                 const float* hout, void* out) {
  int b = blockIdx.x;
  int t = threadIdx.x;  // 256 threads
  __shared__ float c1w[400];
  __shared__ short tok_s[SS];
  __shared__ float pav[3][80];
  __shared__ float avg[80];
  __shared__ float cpart[2][100];
  __shared__ float merged[228];
  __shared__ float fpart[4][64];
  __shared__ float fc1v[64];
  __shared__ float f2p[2][64];
  __shared__ int mode_sh;

  if (t == 0) mode_sh = 1;
  __syncthreads();
  {
    float v = bf2f(((const u16*)bvec)[t]);
    if (!(fabsf(v) < 1000.0f)) atomicAnd(&mode_sh, 0);
  }
  __syncthreads();
  int mode = mode_sh;

  for (int i = t; i < 400; i += 256) c1w[i] = ldw(conv1_w, i, mode);
  for (int s = t; s < SS; s += 256) tok_s[s] = toks[(size_t)b * SS + s];
  __syncthreads();

  int len = lens[b];
  int bw = len >> 2;
  // ragged 4-bin mean: 240 threads = 80 (k,cc) units x 3 segments; 4 independent
  // partial-sum chains per thread so the tok->c1w dependent LDS reads pipeline.
  if (t < 240) {
    int seg = t / 80;
    int u = t - seg * 80;
    int k = u / 20, cc = u % 20;
    int base = k * bw;
    int s0 = base + (seg * bw) / 3;
    int s1 = base + ((seg + 1) * bw) / 3;
    float p0 = 0.f, p1 = 0.f, p2 = 0.f, p3 = 0.f;
    int s = s0;
    for (; s + 4 <= s1; s += 4) {
      // faithful torch reshape: flat f = s*20+cc of the [20,1024] map
      int f0 = s * 20 + cc, f1 = f0 + 20, f2 = f0 + 40, f3 = f0 + 60;
      int tk0 = tok_s[f0 & 1023];
      int tk1 = tok_s[f1 & 1023];
      int tk2 = tok_s[f2 & 1023];
      int tk3 = tok_s[f3 & 1023];
      if (tk0 >= 0) p0 += c1w[(f0 >> 10) * 20 + tk0];
      if (tk1 >= 0) p1 += c1w[(f1 >> 10) * 20 + tk1];
      if (tk2 >= 0) p2 += c1w[(f2 >> 10) * 20 + tk2];
      if (tk3 >= 0) p3 += c1w[(f3 >> 10) * 20 + tk3];
    }
    for (; s < s1; ++s) {
      int f = s * 20 + cc;
      int tk = tok_s[f & 1023];
      if (tk >= 0) p0 += c1w[(f >> 10) * 20 + tk];
    }
    pav[seg][u] = (p0 + p1) + (p2 + p3);
  }
  __syncthreads();
  if (t < 80) avg[t] = (pav[0][t] + pav[1][t] + pav[2][t]) / (float)bw;
  __syncthreads();

  // conv2: 200 threads = 100 outputs x 2 K-halves of 40, unroll 8
  if (t < 200) {
    int half = t / 100, o = t - half * 100;
    float dot = 0.f;
    int q0 = half * 40;
#pragma unroll 8
    for (int q = q0; q < q0 + 40; ++q)
      dot = fmaf(avg[q], ldw(conv2_w, o * 80 + q, mode), dot);
    cpart[half][o] = dot;
  }
  if (t < 128) merged[t] = hout[b * 128 + t];  // [h_fw | h_bw]
  __syncthreads();
  if (t < 100) {
    float dot = cpart[0][t] + cpart[1][t] + ldw(conv2_b, t, mode);
    merged[128 + t] = dot > 0.f ? dot : 0.f;  // relu
  }
  __syncthreads();

  // fc1: 256 threads = 64 outputs x 4 K-chunks of 57, unroll 8
  {
    int o = t & 63, ch = t >> 6;
    float v = 0.f;
    int m0 = ch * 57;
#pragma unroll 8
    for (int m = m0; m < m0 + 57; ++m)
      v = fmaf(merged[m], ldw(fc1_w, o * 228 + m, mode), v);
    fpart[ch][o] = v;
  }
  __syncthreads();
  if (t < 64)
    fc1v[t] = fpart[0][t] + fpart[1][t] + fpart[2][t] + fpart[3][t] + ldw(fc1_b, t, mode);
  __syncthreads();

  // fc2: 128 threads compute products, tree-reduce
  if (t < 128) {
    int o = t >> 6, m = t & 63;
    f2p[o][m] = fc1v[m] * ldw(fc2_w, o * 64 + m, mode);
  }
  __syncthreads();
  for (int stp = 32; stp > 0; stp >>= 1) {
    if (t < 128) {
      int o = t >> 6, m = t & 63;
      if (m < stp) f2p[o][m] += f2p[o][m + stp];
    }
    __syncthreads();
  }
  if (t == 0) {
    float x0 = f2p[0][0] + ldw(fc2_b, 0, mode);
    float x1 = f2p[1][0] + ldw(fc2_b, 1, mode);
    float mx = fmaxf(x0, x1);
    float e0 = fexp2(LOG2E * (x0 - mx)), e1 = fexp2(LOG2E * (x1 - mx));
    float inv = frcp(e0 + e1);
    if (mode) {
      ((__hip_bfloat16*)out)[b * 2 + 0] = __float2bfloat16(e0 * inv);
      ((__hip_bfloat16*)out)[b * 2 + 1] = __float2bfloat16(e1 * inv);
    } else {
      ((float*)out)[b * 2 + 0] = e0 * inv;
      ((float*)out)[b * 2 + 1] = e1 * inv;
    }
  }
}

extern "C" void kernel_launch(void* const* d_in, const int* in_sizes, int n_in,
                              void* d_out, int out_size, void* d_ws, size_t ws_size,
                              hipStream_t stream) {
  (void)in_sizes; (void)n_in; (void)out_size; (void)ws_size;
  char* ws = (char*)d_ws;
  int*   lens = (int*)(ws + 256);                             // 2 KB
  short* toks = (short*)(ws + 256 + 2048);                    // 1 MB
  float* hout = (float*)(ws + 256 + 2048 + (size_t)BB * SS * sizeof(short)); // 256 KB

  lstm_kernel<<<256, 256, 0, stream>>>(d_in[0],
                                       d_in[1], d_in[2], d_in[3],
                                       d_in[4], d_in[5], d_in[6],
                                       toks, lens, hout);
  head_kernel<<<BB, 256, 0, stream>>>(d_in[7], d_in[8], d_in[9],
                                      d_in[10], d_in[11], d_in[12], d_in[13],
                                      d_in[3], toks, lens, hout, d_out);
}

// Round 8
// 378.127 us; speedup vs baseline: 1.4708x; 1.0996x over previous
//
#include <hip/hip_runtime.h>
#include <hip/hip_bf16.h>

#define BB 512
#define SS 1024
#define NI 20
#define HH 64
#define NG 256   // 4*H
#define MB4 4    // batch-dirs per lstm block (1 cell per lane)
#define PAD 80   // h-row stride in f16
#define TROW 260 // x-table row stride (floats); [tok][unit][4tt], 16B rows

typedef unsigned short u16;
typedef unsigned int u32;
typedef unsigned long long u64;
typedef _Float16 f16;
typedef f16 f16x8 __attribute__((ext_vector_type(8)));
typedef float f32x4 __attribute__((ext_vector_type(4)));

#define LOG2E 1.4426950408889634f

__device__ __forceinline__ float bf2f(u16 b) { return __uint_as_float(((u32)b) << 16); }
// mode==1: data is bf16; mode==0: data is fp32
__device__ __forceinline__ float ldw(const void* p, int idx, int mode) {
  return mode ? bf2f(((const u16*)p)[idx]) : ((const float*)p)[idx];
}
__device__ __forceinline__ float frcp(float x) { return __builtin_amdgcn_rcpf(x); }
__device__ __forceinline__ float fexp2(float x) { return __builtin_amdgcn_exp2f(x); }

// ---- fused kernel: blocks 0..255 = r0-verbatim BiLSTM; blocks 256..767 =
// head conv path (one batch each), co-resident via LDS union (r5/r7 ledger
// proof: fused lstm 324 == unfused 325 -> conv blocks are FREE; the ~20 us
// regression in r2/r5/r7 was the T-cap's runtime trip count defeating the
// compile-time unroll-2, ~50 cyc/step). This round: r5 architecture with the
// T-cap REMOVED (loop bound back to compile-time SS, r0-verbatim indexing)
// and the dead lens/reduction machinery stripped. b128 wx-table kept
// (conflicts 5.5M->2.9M, time-neutral).
// LSTM: 256 blocks region, 1/CU. Block = (dir, 4 batches). Wave w owns units
// 16w..16w+15, 4 gate types in-lane; lane (l,q) = cell (batch q, unit 16w+l);
// A-rows dup h[l>>2] 4x. x-projection rides MFMA C-init from the LDS table
// (prefetched 1 step ahead, one ds_read_b128). Weights prescaled: i,f,o rows
// by -log2e, g rows by +2log2e (exp2-ready gates).
union __align__(16) SharedU {
  struct __align__(16) {                 // ---- lstm branch (~31.3 KB)
    float table[21 * TROW];              // 21.8 KB; doubles as extract staging
    f16 hbuf[2][MB4][PAD];
    short tok_s[SS * MB4];               // [pos][m], stores tok+1
  } l;
  struct __align__(16) {                 // ---- conv branch (~27.2 KB)
    u32 stg[5120];                       // 20 KB extract staging
    float c1w[400];
    short tok_c[SS];                     // plain tok
    int redc[256];
    float pav[3][80];
    float avg[80];
    float cpart[2][100];
  } c;
};

__global__ __launch_bounds__(256)
void lstm_kernel(const void* in1,
                 const void* Wih_f, const void* Whh_f, const void* b_f,
                 const void* Wih_b, const void* Whh_b, const void* b_b,
                 const void* conv1_w, const void* conv2_w, const void* conv2_b,
                 float* hout, float* c2g) {
  int bx = blockIdx.x;
  int t = threadIdx.x;

  __shared__ SharedU sh;
  __shared__ int mode_sh;

  // ---- mode probe: b_f read as bf16; fp32 shows wild exponents ----
  if (t == 0) mode_sh = 1;
  __syncthreads();
  {
    float v = bf2f(((const u16*)b_f)[t]);
    if (!(fabsf(v) < 1000.0f)) atomicAnd(&mode_sh, 0);
  }
  __syncthreads();
  int mode = mode_sh;

  if (bx < 256) {
    // ================= LSTM branch (r0 verbatim step; no T-cap) =================
    auto& L = sh.l;
    int dir = bx >> 7;
    int b0 = (bx & 127) * MB4;
    int w = t >> 6, lane = t & 63, l = lane & 15, q = lane >> 4;
    int bsel = l >> 2;            // batch whose h this lane's A-row carries
    const void* Wih = dir ? Wih_b : Wih_f;
    const void* Whh = dir ? Whh_b : Whh_f;
    const void* bv  = dir ? b_b   : b_f;

    // ---- token extraction for this block's 4 batches (staged through table) ----
    for (int m = 0; m < MB4; ++m) {
      if (mode) {
        u32* st = (u32*)L.table;
        for (int k0 = 0; k0 < 4; ++k0) {
          const u32* src = (const u32*)in1 + ((size_t)(b0 + m) * SS + k0 * 256) * 10;
#pragma unroll
          for (int i = 0; i < 10; ++i) st[t + i * 256] = src[t + i * 256];  // coalesced
          __syncthreads();
          const u32* row = st + t * 10;
          int tok = -1;
#pragma unroll
          for (int ww = 0; ww < 10; ++ww) {
            u32 u = row[ww];
            if (u & 0xFFFFu) tok = 2 * ww;
            if (u >> 16)     tok = 2 * ww + 1;
          }
          L.tok_s[(k0 * 256 + t) * MB4 + m] = (short)(tok + 1);
          __syncthreads();
        }
      } else {
        float4* st = (float4*)L.table;
        for (int k0 = 0; k0 < 4; ++k0) {
          const float4* src = (const float4*)((const float*)in1 + ((size_t)(b0 + m) * SS + k0 * 256) * 20);
#pragma unroll
          for (int i = 0; i < 5; ++i) st[t + i * 256] = src[t + i * 256];  // coalesced 16B/lane
          __syncthreads();
          const float* row = (const float*)L.table + t * 20;
          int tok = -1;
#pragma unroll
          for (int ww = 0; ww < 20; ++ww)
            if (row[ww] != 0.f) tok = ww;
          L.tok_s[(k0 * 256 + t) * MB4 + m] = (short)(tok + 1);
          __syncthreads();
        }
      }
    }

    // ---- x-projection table: table[tok+1][u][tt] = scl_tt*(W_ih[64tt+u][tok]+b); row 0 = bias ----
    for (int idx = t; idx < 21 * 256; idx += 256) {
      int r = idx >> 8, g = idx & 255;
      float scl = ((g >> 6) == 2) ? (2.f * LOG2E) : (-LOG2E);
      float v = ldw(bv, g, mode);
      if (r > 0) v += ldw(Wih, g * NI + (r - 1), mode);
      L.table[r * TROW + (g & 63) * 4 + (g >> 6)] = scl * v;
    }
    // ---- W_hh B-fragments: n=lane&15 -> gate col (unit 16w+l, type tt), k=q*8+j ----
    f16x8 Bf[4][2];
#pragma unroll
    for (int tt = 0; tt < 4; ++tt) {
      float scl = (tt == 2) ? (2.f * LOG2E) : (-LOG2E);
      int g = 64 * tt + 16 * w + l;
#pragma unroll
      for (int kc = 0; kc < 2; ++kc) {
        f16x8 v;
#pragma unroll
        for (int j = 0; j < 8; ++j)
          v[j] = (f16)(scl * ldw(Whh, g * HH + kc * 32 + q * 8 + j, mode));
        Bf[tt][kc] = v;
      }
    }
    for (int idx = t; idx < 2 * MB4 * PAD; idx += 256)
      ((f16*)L.hbuf)[idx] = (f16)0.f;
    __syncthreads();

    float c_st = 0.f, hlast = 0.f;
    int jj = 16 * w + l;

    // x-pipeline prologue: wx for s=0 (regs), tok for s=1 (reg)
    f32x4 wxc;
    {
      int pos0 = dir ? (SS - 1) : 0;
      wxc = *(const f32x4*)&L.table[(int)L.tok_s[pos0 * MB4 + q] * TROW + jj * 4];
    }
    int tok1;
    {
      int pos1 = dir ? (SS - 2) : 1;
      tok1 = (int)L.tok_s[pos1 * MB4 + q];
    }

#pragma unroll 2
    for (int s = 0; s < SS; ++s) {
      int p = s & 1;
      // critical path: h fragments (A[m=l][k=q*8+j] = h[bsel][k], 4x dup rows)
      f16x8 a0 = *(const f16x8*)&L.hbuf[p][bsel][q * 8];
      f16x8 a1 = *(const f16x8*)&L.hbuf[p][bsel][32 + q * 8];
      // off-path: wx prefetch for s+1 (single b128), tok fetch for s+2
      f32x4 wxn = *(const f32x4*)&L.table[tok1 * TROW + jj * 4];
      {
        int pos2 = (dir ? (SS - 3 - s) : (s + 2)) & (SS - 1);  // wrapped values unused
        tok1 = (int)L.tok_s[pos2 * MB4 + q];
      }

      // r9-verified serial C-chain: C-init = x-projection, 2-deep MFMA per gate type
      f32x4 acc[4];
#pragma unroll
      for (int tt = 0; tt < 4; ++tt) {
        f32x4 ci = {wxc[tt], wxc[tt], wxc[tt], wxc[tt]};
        acc[tt] = __builtin_amdgcn_mfma_f32_16x16x32_f16(a0, Bf[tt][0], ci, 0, 0, 0);
      }
#pragma unroll
      for (int tt = 0; tt < 4; ++tt)
        acc[tt] = __builtin_amdgcn_mfma_f32_16x16x32_f16(a1, Bf[tt][1], acc[tt], 0, 0, 0);

      // activation (verified r6-r13): Ei=e^-i, Ef=e^-f, Eo=e^-o, G=e^2g
      {
        float Ei = fexp2(acc[0][0]);
        float Ef = fexp2(acc[1][0]);
        float G  = fexp2(acc[2][0]);
        float Eo = fexp2(acc[3][0]);
        float Ei1 = Ei + 1.f, Ef1 = Ef + 1.f, G1 = G + 1.f, Gm = G - 1.f;
        float t1 = Ei1 * G1;
        float num = fmaf(c_st, t1, Gm * Ef1);
        float cv = num * frcp(t1 * Ef1);
        c_st = cv;
        float C = fexp2((2.f * LOG2E) * cv);
        float hv = (C - 1.f) * frcp((Eo + 1.f) * (C + 1.f));
        hlast = hv;
        L.hbuf[p ^ 1][q][jj] = (f16)hv;
      }
      __syncthreads();
      wxc = wxn;
    }
    hout[(b0 + q) * 128 + dir * 64 + jj] = hlast;

  } else {
    // ================= head conv branch (one batch; r4/r5-verified) =================
    auto& C = sh.c;
    int b = bx - 256;
    // own extraction: plain tok per position + len
    int cnt = 0;
    if (mode) {
      for (int k0 = 0; k0 < 4; ++k0) {
        const u32* src = (const u32*)in1 + ((size_t)b * SS + k0 * 256) * 10;
#pragma unroll
        for (int i = 0; i < 10; ++i) C.stg[t + i * 256] = src[t + i * 256];  // coalesced
        __syncthreads();
        const u32* row = C.stg + t * 10;
        int tok = -1;
#pragma unroll
        for (int ww = 0; ww < 10; ++ww) {
          u32 u = row[ww];
          if (u & 0xFFFFu) tok = 2 * ww;
          if (u >> 16)     tok = 2 * ww + 1;
        }
        C.tok_c[k0 * 256 + t] = (short)tok;
        cnt += (tok >= 0);
        __syncthreads();
      }
    } else {
      float4* st = (float4*)C.stg;
      for (int k0 = 0; k0 < 4; ++k0) {
        const float4* src = (const float4*)((const float*)in1 + ((size_t)b * SS + k0 * 256) * 20);
#pragma unroll
        for (int i = 0; i < 5; ++i) st[t + i * 256] = src[t + i * 256];  // coalesced 16B/lane
        __syncthreads();
        const float* row = (const float*)C.stg + t * 20;
        int tok = -1;
#pragma unroll
        for (int ww = 0; ww < 20; ++ww)
          if (row[ww] != 0.f) tok = ww;
        C.tok_c[k0 * 256 + t] = (short)tok;
        cnt += (tok >= 0);
        __syncthreads();
      }
    }
    C.redc[t] = cnt;
    __syncthreads();
    for (int stp = 128; stp > 0; stp >>= 1) {
      if (t < stp) C.redc[t] += C.redc[t + stp];
      __syncthreads();
    }
    int len = C.redc[0];
    int bw = len >> 2;

    for (int i = t; i < 400; i += 256) C.c1w[i] = ldw(conv1_w, i, mode);
    __syncthreads();

    // ragged 4-bin mean: 240 threads = 80 (k,cc) units x 3 segments
    if (t < 240) {
      int seg = t / 80;
      int u = t - seg * 80;
      int k = u / 20, cc = u % 20;
      int base = k * bw;
      int s0 = base + (seg * bw) / 3;
      int s1 = base + ((seg + 1) * bw) / 3;
      float p0 = 0.f, p1 = 0.f, p2 = 0.f, p3 = 0.f;
      int s = s0;
      for (; s + 4 <= s1; s += 4) {
        // faithful torch reshape: flat f = s*20+cc of the [20,1024] map
        int f0 = s * 20 + cc, f1 = f0 + 20, f2 = f0 + 40, f3 = f0 + 60;
        int tk0 = C.tok_c[f0 & 1023];
        int tk1 = C.tok_c[f1 & 1023];
        int tk2 = C.tok_c[f2 & 1023];
        int tk3 = C.tok_c[f3 & 1023];
        if (tk0 >= 0) p0 += C.c1w[(f0 >> 10) * 20 + tk0];
        if (tk1 >= 0) p1 += C.c1w[(f1 >> 10) * 20 + tk1];
        if (tk2 >= 0) p2 += C.c1w[(f2 >> 10) * 20 + tk2];
        if (tk3 >= 0) p3 += C.c1w[(f3 >> 10) * 20 + tk3];
      }
      for (; s < s1; ++s) {
        int f = s * 20 + cc;
        int tk = C.tok_c[f & 1023];
        if (tk >= 0) p0 += C.c1w[(f >> 10) * 20 + tk];
      }
      C.pav[seg][u] = (p0 + p1) + (p2 + p3);
    }
    __syncthreads();
    if (t < 80) C.avg[t] = (C.pav[0][t] + C.pav[1][t] + C.pav[2][t]) / (float)bw;
    __syncthreads();

    // conv2: 200 threads = 100 outputs x 2 K-halves of 40
    if (t < 200) {
      int half = t / 100, o = t - half * 100;
      float dot = 0.f;
      int q0 = half * 40;
#pragma unroll 8
      for (int q = q0; q < q0 + 40; ++q)
        dot = fmaf(C.avg[q], ldw(conv2_w, o * 80 + q, mode), dot);
      C.cpart[half][o] = dot;
    }
    __syncthreads();
    if (t < 100) {
      float dot = C.cpart[0][t] + C.cpart[1][t] + ldw(conv2_b, t, mode);
      c2g[b * 100 + t] = dot > 0.f ? dot : 0.f;  // relu'd, biased
    }
  }
}

// ---- fc tail: merged = [hout | c2] -> fc1 -> fc2 -> softmax ----
__global__ __launch_bounds__(256)
void head_kernel(const void* fc1_w, const void* fc1_b,
                 const void* fc2_w, const void* fc2_b,
                 const void* bvec, const float* hout, const float* c2g, void* out) {
  int b = blockIdx.x;
  int t = threadIdx.x;  // 256 threads
  __shared__ float merged[228];
  __shared__ float fpart[4][64];
  __shared__ float fc1v[64];
  __shared__ float f2p[2][64];
  __shared__ int mode_sh;

  if (t == 0) mode_sh = 1;
  __syncthreads();
  {
    float v = bf2f(((const u16*)bvec)[t]);
    if (!(fabsf(v) < 1000.0f)) atomicAnd(&mode_sh, 0);
  }
  __syncthreads();
  int mode = mode_sh;

  if (t < 128) merged[t] = hout[b * 128 + t];          // [h_fw | h_bw]
  else if (t < 228) merged[t] = c2g[b * 100 + (t - 128)];
  __syncthreads();

  // fc1: 256 threads = 64 outputs x 4 K-chunks of 57
  {
    int o = t & 63, ch = t >> 6;
    float v = 0.f;
    int m0 = ch * 57;
#pragma unroll 8
    for (int m = m0; m < m0 + 57; ++m)
      v = fmaf(merged[m], ldw(fc1_w, o * 228 + m, mode), v);
    fpart[ch][o] = v;
  }
  __syncthreads();
  if (t < 64)
    fc1v[t] = fpart[0][t] + fpart[1][t] + fpart[2][t] + fpart[3][t] + ldw(fc1_b, t, mode);
  __syncthreads();

  // fc2: 128 threads compute products, tree-reduce
  if (t < 128) {
    int o = t >> 6, m = t & 63;
    f2p[o][m] = fc1v[m] * ldw(fc2_w, o * 64 + m, mode);
  }
  __syncthreads();
  for (int stp = 32; stp > 0; stp >>= 1) {
    if (t < 128) {
      int o = t >> 6, m = t & 63;
      if (m < stp) f2p[o][m] += f2p[o][m + stp];
    }
    __syncthreads();
  }
  if (t == 0) {
    float x0 = f2p[0][0] + ldw(fc2_b, 0, mode);
    float x1 = f2p[1][0] + ldw(fc2_b, 1, mode);
    float mx = fmaxf(x0, x1);
    float e0 = fexp2(LOG2E * (x0 - mx)), e1 = fexp2(LOG2E * (x1 - mx));
    float inv = frcp(e0 + e1);
    if (mode) {
      ((__hip_bfloat16*)out)[b * 2 + 0] = __float2bfloat16(e0 * inv);
      ((__hip_bfloat16*)out)[b * 2 + 1] = __float2bfloat16(e1 * inv);
    } else {
      ((float*)out)[b * 2 + 0] = e0 * inv;
      ((float*)out)[b * 2 + 1] = e1 * inv;
    }
  }
}

extern "C" void kernel_launch(void* const* d_in, const int* in_sizes, int n_in,
                              void* d_out, int out_size, void* d_ws, size_t ws_size,
                              hipStream_t stream) {
  (void)in_sizes; (void)n_in; (void)out_size; (void)ws_size;
  char* ws = (char*)d_ws;
  float* hout = (float*)(ws + 256);                          // 256 KB
  float* c2g  = (float*)(ws + 256 + (size_t)BB * 128 * 4);   // 200 KB

  lstm_kernel<<<768, 256, 0, stream>>>(d_in[0],
                                       d_in[1], d_in[2], d_in[3],
                                       d_in[4], d_in[5], d_in[6],
                                       d_in[7], d_in[8], d_in[9],
                                       hout, c2g);
  head_kernel<<<BB, 256, 0, stream>>>(d_in[10], d_in[11], d_in[12], d_in[13],
                                      d_in[3], hout, c2g, d_out);
}

// Round 9
// 370.896 us; speedup vs baseline: 1.4995x; 1.0195x over previous
//
#include <hip/hip_runtime.h>
#include <hip/hip_bf16.h>

#define BB 512
#define SS 1024
#define NI 20
#define HH 64
#define NG 256   // 4*H
#define MB4 4    // batch-dirs per lstm block (1 cell per lane)
#define PAD 80   // h-row stride in f16
#define TROW 260 // x-table row stride (floats); [tok][unit][4tt], 16B rows

typedef unsigned short u16;
typedef unsigned int u32;
typedef unsigned long long u64;
typedef _Float16 f16;
typedef f16 f16x8 __attribute__((ext_vector_type(8)));
typedef float f32x4 __attribute__((ext_vector_type(4)));

#define LOG2E 1.4426950408889634f

__device__ __forceinline__ float bf2f(u16 b) { return __uint_as_float(((u32)b) << 16); }
// mode==1: data is bf16; mode==0: data is fp32
__device__ __forceinline__ float ldw(const void* p, int idx, int mode) {
  return mode ? bf2f(((const u16*)p)[idx]) : ((const float*)p)[idx];
}
__device__ __forceinline__ float frcp(float x) { return __builtin_amdgcn_rcpf(x); }
__device__ __forceinline__ float fexp2(float x) { return __builtin_amdgcn_exp2f(x); }

// ---- fused kernel: blocks 0..255 = BiLSTM; blocks 256..767 = head conv path
// (one batch each), co-resident via LDS union (r8-verified: conv blocks are
// FREE -- lstm dispatch 303 us fused == unfused r0). Loop bound is the
// compile-time SS (r8 lesson: runtime trip count = +20 us).
// This round: step body = r2's two latency cuts, now isolated from the toxic
// T-cap: (1) parallel-K MFMA pair (zero-C hoisted; removes one dependent MFMA
// latency + the 16 ci-splat v_movs; 8 scalar adds assemble the gates),
// (2) d-state activation (d = 2log2e*c; drops a mul feeding the second exp2).
// Ledger: r2 = these trims + T-cap = 320; T-cap alone = +22 -> trims ~ -3.
// LSTM: 256 blocks, 1/CU. Block = (dir, 4 batches). Wave w owns units
// 16w..16w+15, 4 gate types in-lane; lane (l,q) = cell (batch q, unit 16w+l);
// A-rows dup h[l>>2] 4x. x-projection via one ds_read_b128 from the
// [tok][unit][4tt] LDS table (prefetched 1 step ahead). Weights prescaled:
// i,f,o rows by -log2e, g rows by +2log2e (exp2-ready gates).
union __align__(16) SharedU {
  struct __align__(16) {                 // ---- lstm branch (~31.3 KB)
    float table[21 * TROW];              // 21.8 KB; doubles as extract staging
    f16 hbuf[2][MB4][PAD];
    short tok_s[SS * MB4];               // [pos][m], stores tok+1
  } l;
  struct __align__(16) {                 // ---- conv branch (~27.2 KB)
    u32 stg[5120];                       // 20 KB extract staging
    float c1w[400];
    short tok_c[SS];                     // plain tok
    int redc[256];
    float pav[3][80];
    float avg[80];
    float cpart[2][100];
  } c;
};

__global__ __launch_bounds__(256)
void lstm_kernel(const void* in1,
                 const void* Wih_f, const void* Whh_f, const void* b_f,
                 const void* Wih_b, const void* Whh_b, const void* b_b,
                 const void* conv1_w, const void* conv2_w, const void* conv2_b,
                 float* hout, float* c2g) {
  int bx = blockIdx.x;
  int t = threadIdx.x;

  __shared__ SharedU sh;
  __shared__ int mode_sh;

  // ---- mode probe: b_f read as bf16; fp32 shows wild exponents ----
  if (t == 0) mode_sh = 1;
  __syncthreads();
  {
    float v = bf2f(((const u16*)b_f)[t]);
    if (!(fabsf(v) < 1000.0f)) atomicAnd(&mode_sh, 0);
  }
  __syncthreads();
  int mode = mode_sh;

  if (bx < 256) {
    // ================= LSTM branch =================
    auto& L = sh.l;
    int dir = bx >> 7;
    int b0 = (bx & 127) * MB4;
    int w = t >> 6, lane = t & 63, l = lane & 15, q = lane >> 4;
    int bsel = l >> 2;            // batch whose h this lane's A-row carries
    const void* Wih = dir ? Wih_b : Wih_f;
    const void* Whh = dir ? Whh_b : Whh_f;
    const void* bv  = dir ? b_b   : b_f;

    // ---- token extraction for this block's 4 batches (staged through table) ----
    for (int m = 0; m < MB4; ++m) {
      if (mode) {
        u32* st = (u32*)L.table;
        for (int k0 = 0; k0 < 4; ++k0) {
          const u32* src = (const u32*)in1 + ((size_t)(b0 + m) * SS + k0 * 256) * 10;
#pragma unroll
          for (int i = 0; i < 10; ++i) st[t + i * 256] = src[t + i * 256];  // coalesced
          __syncthreads();
          const u32* row = st + t * 10;
          int tok = -1;
#pragma unroll
          for (int ww = 0; ww < 10; ++ww) {
            u32 u = row[ww];
            if (u & 0xFFFFu) tok = 2 * ww;
            if (u >> 16)     tok = 2 * ww + 1;
          }
          L.tok_s[(k0 * 256 + t) * MB4 + m] = (short)(tok + 1);
          __syncthreads();
        }
      } else {
        float4* st = (float4*)L.table;
        for (int k0 = 0; k0 < 4; ++k0) {
          const float4* src = (const float4*)((const float*)in1 + ((size_t)(b0 + m) * SS + k0 * 256) * 20);
#pragma unroll
          for (int i = 0; i < 5; ++i) st[t + i * 256] = src[t + i * 256];  // coalesced 16B/lane
          __syncthreads();
          const float* row = (const float*)L.table + t * 20;
          int tok = -1;
#pragma unroll
          for (int ww = 0; ww < 20; ++ww)
            if (row[ww] != 0.f) tok = ww;
          L.tok_s[(k0 * 256 + t) * MB4 + m] = (short)(tok + 1);
          __syncthreads();
        }
      }
    }

    // ---- x-projection table: table[tok+1][u][tt] = scl_tt*(W_ih[64tt+u][tok]+b); row 0 = bias ----
    for (int idx = t; idx < 21 * 256; idx += 256) {
      int r = idx >> 8, g = idx & 255;
      float scl = ((g >> 6) == 2) ? (2.f * LOG2E) : (-LOG2E);
      float v = ldw(bv, g, mode);
      if (r > 0) v += ldw(Wih, g * NI + (r - 1), mode);
      L.table[r * TROW + (g & 63) * 4 + (g >> 6)] = scl * v;
    }
    // ---- W_hh B-fragments: n=lane&15 -> gate col (unit 16w+l, type tt), k=q*8+j ----
    f16x8 Bf[4][2];
#pragma unroll
    for (int tt = 0; tt < 4; ++tt) {
      float scl = (tt == 2) ? (2.f * LOG2E) : (-LOG2E);
      int g = 64 * tt + 16 * w + l;
#pragma unroll
      for (int kc = 0; kc < 2; ++kc) {
        f16x8 v;
#pragma unroll
        for (int j = 0; j < 8; ++j)
          v[j] = (f16)(scl * ldw(Whh, g * HH + kc * 32 + q * 8 + j, mode));
        Bf[tt][kc] = v;
      }
    }
    for (int idx = t; idx < 2 * MB4 * PAD; idx += 256)
      ((f16*)L.hbuf)[idx] = (f16)0.f;
    __syncthreads();

    float d_st = 0.f, hlast = 0.f;   // d = 2*log2e*c
    int jj = 16 * w + l;

    // x-pipeline prologue: wx for s=0 (regs), tok for s=1 (reg)
    f32x4 wxc;
    {
      int pos0 = dir ? (SS - 1) : 0;
      wxc = *(const f32x4*)&L.table[(int)L.tok_s[pos0 * MB4 + q] * TROW + jj * 4];
    }
    int tok1;
    {
      int pos1 = dir ? (SS - 2) : 1;
      tok1 = (int)L.tok_s[pos1 * MB4 + q];
    }

    const f32x4 Z = {0.f, 0.f, 0.f, 0.f};

#pragma unroll 2
    for (int s = 0; s < SS; ++s) {
      int p = s & 1;
      // critical path: h fragments (A[m=l][k=q*8+j] = h[bsel][k], 4x dup rows)
      f16x8 a0 = *(const f16x8*)&L.hbuf[p][bsel][q * 8];
      f16x8 a1 = *(const f16x8*)&L.hbuf[p][bsel][32 + q * 8];
      // off-path: wx prefetch for s+1 (single b128), tok fetch for s+2
      f32x4 wxn = *(const f32x4*)&L.table[tok1 * TROW + jj * 4];
      {
        int pos2 = (dir ? (SS - 3 - s) : (s + 2)) & (SS - 1);  // wrapped values unused
        tok1 = (int)L.tok_s[pos2 * MB4 + q];
      }

      // parallel-K MFMA pair per gate type (zero-C hoisted; one dependent MFMA
      // latency removed from the pole; gates assembled by scalar adds)
      f32x4 accA[4], accB[4];
#pragma unroll
      for (int tt = 0; tt < 4; ++tt)
        accA[tt] = __builtin_amdgcn_mfma_f32_16x16x32_f16(a0, Bf[tt][0], Z, 0, 0, 0);
#pragma unroll
      for (int tt = 0; tt < 4; ++tt)
        accB[tt] = __builtin_amdgcn_mfma_f32_16x16x32_f16(a1, Bf[tt][1], Z, 0, 0, 0);

      float g_i = accA[0][0] + accB[0][0] + wxc[0];
      float g_f = accA[1][0] + accB[1][0] + wxc[1];
      float g_g = accA[2][0] + accB[2][0] + wxc[2];
      float g_o = accA[3][0] + accB[3][0] + wxc[3];

      // d-state activation (algebraically == r0 form): Ei=e^-i, Ef=e^-f,
      // Eo=e^-o, G=e^2g; F=sigma(f); Itg=sigma(i)*tanh(g);
      // d' = F*d + 2log2e*Itg (d = 2log2e*c); h = tanh(c)*sigma(o)
      {
        float Ei = fexp2(g_i);
        float Ef = fexp2(g_f);
        float G  = fexp2(g_g);
        float Eo = fexp2(g_o);
        float F   = frcp(Ef + 1.f);
        float Itg = (G - 1.f) * frcp((Ei + 1.f) * (G + 1.f));
        float dnew = fmaf(F, d_st, (2.f * LOG2E) * Itg);
        d_st = dnew;
        float C = fexp2(dnew);
        float hv = (C - 1.f) * frcp((Eo + 1.f) * (C + 1.f));
        hlast = hv;
        L.hbuf[p ^ 1][q][jj] = (f16)hv;
      }
      __syncthreads();
      wxc = wxn;
    }
    hout[(b0 + q) * 128 + dir * 64 + jj] = hlast;

  } else {
    // ================= head conv branch (one batch; r8-verified) =================
    auto& C = sh.c;
    int b = bx - 256;
    // own extraction: plain tok per position + len
    int cnt = 0;
    if (mode) {
      for (int k0 = 0; k0 < 4; ++k0) {
        const u32* src = (const u32*)in1 + ((size_t)b * SS + k0 * 256) * 10;
#pragma unroll
        for (int i = 0; i < 10; ++i) C.stg[t + i * 256] = src[t + i * 256];  // coalesced
        __syncthreads();
        const u32* row = C.stg + t * 10;
        int tok = -1;
#pragma unroll
        for (int ww = 0; ww < 10; ++ww) {
          u32 u = row[ww];
          if (u & 0xFFFFu) tok = 2 * ww;
          if (u >> 16)     tok = 2 * ww + 1;
        }
        C.tok_c[k0 * 256 + t] = (short)tok;
        cnt += (tok >= 0);
        __syncthreads();
      }
    } else {
      float4* st = (float4*)C.stg;
      for (int k0 = 0; k0 < 4; ++k0) {
        const float4* src = (const float4*)((const float*)in1 + ((size_t)b * SS + k0 * 256) * 20);
#pragma unroll
        for (int i = 0; i < 5; ++i) st[t + i * 256] = src[t + i * 256];  // coalesced 16B/lane
        __syncthreads();
        const float* row = (const float*)C.stg + t * 20;
        int tok = -1;
#pragma unroll
        for (int ww = 0; ww < 20; ++ww)
          if (row[ww] != 0.f) tok = ww;
        C.tok_c[k0 * 256 + t] = (short)tok;
        cnt += (tok >= 0);
        __syncthreads();
      }
    }
    C.redc[t] = cnt;
    __syncthreads();
    for (int stp = 128; stp > 0; stp >>= 1) {
      if (t < stp) C.redc[t] += C.redc[t + stp];
      __syncthreads();
    }
    int len = C.redc[0];
    int bw = len >> 2;

    for (int i = t; i < 400; i += 256) C.c1w[i] = ldw(conv1_w, i, mode);
    __syncthreads();

    // ragged 4-bin mean: 240 threads = 80 (k,cc) units x 3 segments
    if (t < 240) {
      int seg = t / 80;
      int u = t - seg * 80;
      int k = u / 20, cc = u % 20;
      int base = k * bw;
      int s0 = base + (seg * bw) / 3;
      int s1 = base + ((seg + 1) * bw) / 3;
      float p0 = 0.f, p1 = 0.f, p2 = 0.f, p3 = 0.f;
      int s = s0;
      for (; s + 4 <= s1; s += 4) {
        // faithful torch reshape: flat f = s*20+cc of the [20,1024] map
        int f0 = s * 20 + cc, f1 = f0 + 20, f2 = f0 + 40, f3 = f0 + 60;
        int tk0 = C.tok_c[f0 & 1023];
        int tk1 = C.tok_c[f1 & 1023];
        int tk2 = C.tok_c[f2 & 1023];
        int tk3 = C.tok_c[f3 & 1023];
        if (tk0 >= 0) p0 += C.c1w[(f0 >> 10) * 20 + tk0];
        if (tk1 >= 0) p1 += C.c1w[(f1 >> 10) * 20 + tk1];
        if (tk2 >= 0) p2 += C.c1w[(f2 >> 10) * 20 + tk2];
        if (tk3 >= 0) p3 += C.c1w[(f3 >> 10) * 20 + tk3];
      }
      for (; s < s1; ++s) {
        int f = s * 20 + cc;
        int tk = C.tok_c[f & 1023];
        if (tk >= 0) p0 += C.c1w[(f >> 10) * 20 + tk];
      }
      C.pav[seg][u] = (p0 + p1) + (p2 + p3);
    }
    __syncthreads();
    if (t < 80) C.avg[t] = (C.pav[0][t] + C.pav[1][t] + C.pav[2][t]) / (float)bw;
    __syncthreads();

    // conv2: 200 threads = 100 outputs x 2 K-halves of 40
    if (t < 200) {
      int half = t / 100, o = t - half * 100;
      float dot = 0.f;
      int q0 = half * 40;
#pragma unroll 8
      for (int q = q0; q < q0 + 40; ++q)
        dot = fmaf(C.avg[q], ldw(conv2_w, o * 80 + q, mode), dot);
      C.cpart[half][o] = dot;
    }
    __syncthreads();
    if (t < 100) {
      float dot = C.cpart[0][t] + C.cpart[1][t] + ldw(conv2_b, t, mode);
      c2g[b * 100 + t] = dot > 0.f ? dot : 0.f;  // relu'd, biased
    }
  }
}

// ---- fc tail: merged = [hout | c2] -> fc1 -> fc2 -> softmax ----
__global__ __launch_bounds__(256)
void head_kernel(const void* fc1_w, const void* fc1_b,
                 const void* fc2_w, const void* fc2_b,
                 const void* bvec, const float* hout, const float* c2g, void* out) {
  int b = blockIdx.x;
  int t = threadIdx.x;  // 256 threads
  __shared__ float merged[228];
  __shared__ float fpart[4][64];
  __shared__ float fc1v[64];
  __shared__ float f2p[2][64];
  __shared__ int mode_sh;

  if (t == 0) mode_sh = 1;
  __syncthreads();
  {
    float v = bf2f(((const u16*)bvec)[t]);
    if (!(fabsf(v) < 1000.0f)) atomicAnd(&mode_sh, 0);
  }
  __syncthreads();
  int mode = mode_sh;

  if (t < 128) merged[t] = hout[b * 128 + t];          // [h_fw | h_bw]
  else if (t < 228) merged[t] = c2g[b * 100 + (t - 128)];
  __syncthreads();

  // fc1: 256 threads = 64 outputs x 4 K-chunks of 57
  {
    int o = t & 63, ch = t >> 6;
    float v = 0.f;
    int m0 = ch * 57;
#pragma unroll 8
    for (int m = m0; m < m0 + 57; ++m)
      v = fmaf(merged[m], ldw(fc1_w, o * 228 + m, mode), v);
    fpart[ch][o] = v;
  }
  __syncthreads();
  if (t < 64)
    fc1v[t] = fpart[0][t] + fpart[1][t] + fpart[2][t] + fpart[3][t] + ldw(fc1_b, t, mode);
  __syncthreads();

  // fc2: 128 threads compute products, tree-reduce
  if (t < 128) {
    int o = t >> 6, m = t & 63;
    f2p[o][m] = fc1v[m] * ldw(fc2_w, o * 64 + m, mode);
  }
  __syncthreads();
  for (int stp = 32; stp > 0; stp >>= 1) {
    if (t < 128) {
      int o = t >> 6, m = t & 63;
      if (m < stp) f2p[o][m] += f2p[o][m + stp];
    }
    __syncthreads();
  }
  if (t == 0) {
    float x0 = f2p[0][0] + ldw(fc2_b, 0, mode);
    float x1 = f2p[1][0] + ldw(fc2_b, 1, mode);
    float mx = fmaxf(x0, x1);
    float e0 = fexp2(LOG2E * (x0 - mx)), e1 = fexp2(LOG2E * (x1 - mx));
    float inv = frcp(e0 + e1);
    if (mode) {
      ((__hip_bfloat16*)out)[b * 2 + 0] = __float2bfloat16(e0 * inv);
      ((__hip_bfloat16*)out)[b * 2 + 1] = __float2bfloat16(e1 * inv);
    } else {
      ((float*)out)[b * 2 + 0] = e0 * inv;
      ((float*)out)[b * 2 + 1] = e1 * inv;
    }
  }
}

extern "C" void kernel_launch(void* const* d_in, const int* in_sizes, int n_in,
                              void* d_out, int out_size, void* d_ws, size_t ws_size,
                              hipStream_t stream) {
  (void)in_sizes; (void)n_in; (void)out_size; (void)ws_size;
  char* ws = (char*)d_ws;
  float* hout = (float*)(ws + 256);                          // 256 KB
  float* c2g  = (float*)(ws + 256 + (size_t)BB * 128 * 4);   // 200 KB

  lstm_kernel<<<768, 256, 0, stream>>>(d_in[0],
                                       d_in[1], d_in[2], d_in[3],
                                       d_in[4], d_in[5], d_in[6],
                                       d_in[7], d_in[8], d_in[9],
                                       hout, c2g);
  head_kernel<<<BB, 256, 0, stream>>>(d_in[10], d_in[11], d_in[12], d_in[13],
                                      d_in[3], hout, c2g, d_out);
}